// Round 13
// baseline (563.888 us; speedup 1.0000x reference)
//
#include <hip/hip_runtime.h>
#include <cstdint>
#include <cstddef>

// ---------------------------------------------------------------------------
// MaskedContextEncoder: B=32 IMG=512 P=16 CIN=4 D=256 DEPTH=4 H=8 FF=2048
// Round 13: k_gemm_ln8 = 64x256 tile / 8 waves (2Mx4N) for out-proj+LN1 and
// ff2+LN2. Halves per-XCD W re-read traffic (512->256 blocks; ff2 W-read
// floor 15->7.5us) while keeping 8 waves/CU (R12's win; R7's 4-wave 64-row
// variant lacked waves, not bandwidth). dbuf + counted vmcnt(5).
// Everything else identical to R12 (552.6us).
// ---------------------------------------------------------------------------

#define Bq 32
#define Dm 256
#define Lq 512
#define Hh 8
#define FFq 2048
#define Mtok (Bq * Lq)   // 16384 rows

typedef __attribute__((ext_vector_type(8))) short  short8;
typedef __attribute__((ext_vector_type(4))) float  f32x4;
typedef __attribute__((ext_vector_type(4))) unsigned int u32x4;
typedef __attribute__((ext_vector_type(2))) unsigned int u32x2;

static __device__ __forceinline__ unsigned short f2bf(float f) {
    unsigned int u = __float_as_uint(f);
    unsigned int r = (u + 0x7FFFu + ((u >> 16) & 1u)) >> 16;
    return (unsigned short)r;
}
static __device__ __forceinline__ unsigned int pk2bf(float lo, float hi) {
    return (unsigned int)f2bf(lo) | ((unsigned int)f2bf(hi) << 16);
}

static __device__ __forceinline__ void gload_lds16(const void* g, void* l) {
    __builtin_amdgcn_global_load_lds(
        (const __attribute__((address_space(1))) unsigned int*)g,
        (__attribute__((address_space(3))) unsigned int*)l, 16, 0, 0);
}

// chunked bijective XCD swizzle: grid%8==0; XCD x gets logical ids
// [x*(grid/8), (x+1)*(grid/8)).
static __device__ __forceinline__ int xcd_swz(int id, int grid) {
    return (id & 7) * (grid >> 3) + (id >> 3);
}

// --------------------------- order (compaction) ----------------------------
__global__ __launch_bounds__(1024) void k_order(const float* __restrict__ mask,
                                                int* __restrict__ order) {
    const int b = blockIdx.x;
    const int n = threadIdx.x;
    const float v = mask[(size_t)b * 262144 + (size_t)(n >> 5) * 8192 + (n & 31) * 16];
    const bool sel = v < 0.5f;
    const unsigned long long ball = __ballot(sel);
    const int wave = n >> 6, lane = n & 63;
    __shared__ int wsum[16];
    __shared__ int wpre[16];
    if (lane == 0) wsum[wave] = __popcll(ball);
    __syncthreads();
    if (n == 0) {
        int s = 0;
        for (int i = 0; i < 16; ++i) { wpre[i] = s; s += wsum[i]; }
    }
    __syncthreads();
    const int rank = wpre[wave] + __popcll(ball & ((1ull << lane) - 1ull));
    if (sel) order[b * Lq + rank] = n;
}

// ----------------- gather: patches -> bf16 A, pos rows -> f32 ---------------
__global__ __launch_bounds__(256) void k_gather(const float* __restrict__ image,
                                                const int* __restrict__ order,
                                                const float* __restrict__ pos,
                                                unsigned short* __restrict__ patchA,
                                                float* __restrict__ posG) {
    __shared__ int pn[16];
    const int tid = threadIdx.x;
    const int tok0 = blockIdx.x * 16;
    if (tid < 16) pn[tid] = order[tok0 + tid];
    __syncthreads();
    const int lane = tid & 63, w4 = tid >> 6;
    const int rr = lane >> 2, col4 = (lane & 3) << 2;
#pragma unroll
    for (int it = 0; it < 12; ++it) {
        const int s = it * 4 + w4;          // 0..47 slabs (t,c)
        const int t = s / 3, cch = s % 3;
        const int n = pn[t];
        const int b = (tok0 + t) >> 9;
        const int pi = n >> 5, pj = n & 31;
        const float4 v = *(const float4*)&image[
            (((size_t)b * 3 + cch) * 512 + pi * 16 + rr) * 512 + pj * 16 + col4];
        unsigned int pk[2] = {pk2bf(v.x, v.y), pk2bf(v.z, v.w)};
        *(uint2*)&patchA[(size_t)(tok0 + t) * 768 + cch * 256 + rr * 16 + col4] =
            *(uint2*)pk;
    }
#pragma unroll
    for (int it = 0; it < 4; ++it) {
        const int t = it * 4 + w4;
        *(float4*)&posG[(size_t)(tok0 + t) * Dm + lane * 4] =
            *(const float4*)&pos[(size_t)pn[t] * Dm + lane * 4];
    }
}

// ------------- conv weight: f32 [256][1024] -> bf16 [256][768] --------------
__global__ __launch_bounds__(256) void k_wembed(const float* __restrict__ conv_w,
                                                unsigned short* __restrict__ W16) {
    const int i = blockIdx.x * 256 + threadIdx.x;
    const int d = i / 96, k8 = (i % 96) * 8;
    const float4 a = *(const float4*)&conv_w[(size_t)d * 1024 + k8];
    const float4 b = *(const float4*)&conv_w[(size_t)d * 1024 + k8 + 4];
    unsigned int pk[4] = {pk2bf(a.x, a.y), pk2bf(a.z, a.w),
                          pk2bf(b.x, b.y), pk2bf(b.z, b.w)};
    *(uint4*)&W16[(size_t)d * 768 + k8] = *(uint4*)pk;
}

// ---------- merged weight prep: f32 [K][N] -> bf16 [N][K], all weights ------
__global__ __launch_bounds__(256) void k_wprep_all(const float* __restrict__ qkv_w,
                                                   const float* __restrict__ out_w,
                                                   const float* __restrict__ ff1_w,
                                                   const float* __restrict__ ff2_w,
                                                   unsigned short* __restrict__ Wq,
                                                   unsigned short* __restrict__ Wo,
                                                   unsigned short* __restrict__ Wf1,
                                                   unsigned short* __restrict__ Wf2) {
    __shared__ float tile[64][65];
    int idx = blockIdx.x;
    const float* W; unsigned short* WT; int K, N, l, r;
    if (idx < 192)      { l = idx / 48;          r = idx % 48;  K = 256;  N = 768;  W = qkv_w; WT = Wq; }
    else if (idx < 256) { l = (idx - 192) / 16;  r = idx & 15;  K = 256;  N = 256;  W = out_w; WT = Wo; }
    else if (idx < 768) { l = (idx - 256) / 128; r = (idx - 256) % 128; K = 256;  N = 2048; W = ff1_w; WT = Wf1; }
    else                { l = (idx - 768) / 128; r = (idx - 768) % 128; K = 2048; N = 256;  W = ff2_w; WT = Wf2; }
    const int nTiles = N >> 6;
    const int n0 = (r % nTiles) * 64, k0 = (r / nTiles) * 64;
    W  += (size_t)l * K * N;
    WT += (size_t)l * K * N;
    const int t = threadIdx.x;
#pragma unroll
    for (int it = 0; it < 4; ++it) {
        const int rr = (t >> 4) + it * 16, c4 = (t & 15) * 4;
        *(float4*)&tile[rr][c4] = *(const float4*)&W[(size_t)(k0 + rr) * N + n0 + c4];
    }
    __syncthreads();
    const int n = t & 63, kq = t >> 6;
    unsigned short pk[16];
#pragma unroll
    for (int j = 0; j < 16; ++j) pk[j] = f2bf(tile[kq * 16 + j][n]);
    unsigned short* dst = &WT[(size_t)(n0 + n) * K + k0 + kq * 16];
    *(uint4*)dst       = *(uint4*)&pk[0];
    *(uint4*)(dst + 8) = *(uint4*)&pk[8];
}

// ------------------------------ bf16 MFMA GEMM ------------------------------
// 128x128 tile, BK=64, 4 waves (2x2). Used for the embed GEMM.
template <bool RELU, bool RES, bool OUT32, bool OUT16, int NBUF, bool SWZ>
__global__ __launch_bounds__(256) void k_mgemm(const unsigned short* __restrict__ A,
                                               const unsigned short* __restrict__ W,
                                               const float* __restrict__ bias,
                                               const float* __restrict__ R,
                                               float* __restrict__ C32,
                                               unsigned short* __restrict__ C16,
                                               int ntiles, int M, int N, int K) {
    __shared__ unsigned short Al[128 * 64 * NBUF];
    __shared__ unsigned short Bl[128 * 64 * NBUF];
    const int tid = threadIdx.x;
    const int lane = tid & 63, wave = tid >> 6;
    const int wm = wave >> 1, wn = wave & 1;
    int id = blockIdx.x;
    if constexpr (SWZ) id = xcd_swz(id, (int)gridDim.x);
    const int n0 = (id % ntiles) * 128, m0 = (id / ntiles) * 128;
    const int c = lane >> 4, a15 = lane & 15;
    f32x4 acc[4][4] = {};

    const int srow = lane >> 3;
    const int sgran = (lane & 7) ^ srow;   // pre-swizzled source granule
    const int KT = K >> 6;

    auto stage = [&](int buf, int kt) {
        const int k0 = kt << 6;
#pragma unroll
        for (int q = 0; q < 4; ++q) {
            const int rbase = wave * 32 + q * 8;
            gload_lds16(A + (size_t)(m0 + rbase + srow) * K + k0 + sgran * 8,
                        &Al[buf * 8192 + rbase * 64]);
            gload_lds16(W + (size_t)(n0 + rbase + srow) * K + k0 + sgran * 8,
                        &Bl[buf * 8192 + rbase * 64]);
        }
    };
    auto compute = [&](int buf) {
        const int bo = buf * 8192;
#pragma unroll
        for (int kc = 0; kc < 2; ++kc) {
            short8 af[4], bf[4];
#pragma unroll
            for (int fm = 0; fm < 4; ++fm) {
                const int row = wm * 64 + fm * 16 + a15;
                const int slot = (kc * 4 + c) ^ (row & 7);
                af[fm] = *(const short8*)&Al[bo + row * 64 + slot * 8];
            }
#pragma unroll
            for (int fn = 0; fn < 4; ++fn) {
                const int row = wn * 64 + fn * 16 + a15;
                const int slot = (kc * 4 + c) ^ (row & 7);
                bf[fn] = *(const short8*)&Bl[bo + row * 64 + slot * 8];
            }
#pragma unroll
            for (int fm = 0; fm < 4; ++fm)
#pragma unroll
                for (int fn = 0; fn < 4; ++fn)
                    acc[fm][fn] = __builtin_amdgcn_mfma_f32_16x16x32_bf16(
                        af[fm], bf[fn], acc[fm][fn], 0, 0, 0);
        }
    };

    if constexpr (NBUF == 2) {
        stage(0, 0);
        for (int kt = 0; kt < KT; ++kt) {
            const int cur = kt & 1;
            if (kt + 1 < KT) {
                stage(cur ^ 1, kt + 1);
                asm volatile("s_waitcnt vmcnt(8)" ::: "memory");
            } else {
                asm volatile("s_waitcnt vmcnt(0)" ::: "memory");
            }
            __builtin_amdgcn_s_barrier();
            compute(cur);
            __builtin_amdgcn_s_barrier();
        }
    } else {
        for (int kt = 0; kt < KT; ++kt) {
            __syncthreads();
            stage(0, kt);
            __syncthreads();
            compute(0);
        }
    }
#pragma unroll
    for (int fn = 0; fn < 4; ++fn) {
        const int col = n0 + wn * 64 + fn * 16 + a15;
        const float bv = bias[col];
#pragma unroll
        for (int fm = 0; fm < 4; ++fm) {
            const int mrow = m0 + wm * 64 + fm * 16 + c * 4;
#pragma unroll
            for (int r = 0; r < 4; ++r) {
                float v = acc[fm][fn][r] + bv;
                if constexpr (RES) v += R[(size_t)(mrow + r) * N + col];
                if constexpr (RELU) v = fmaxf(v, 0.f);
                if constexpr (OUT32) C32[(size_t)(mrow + r) * N + col] = v;
                if constexpr (OUT16) C16[(size_t)(mrow + r) * N + col] = f2bf(v);
            }
        }
    }
}

// --------------------- 8-wave 256x128-tile bf16 MFMA GEMM -------------------
// 512 thr, 8 waves (4M x 2N), BK=64, single-buffer. Slab-aligned swizzle.
template <bool RELU, bool OUT16>
__global__ __launch_bounds__(512) void k_mgemm8(const unsigned short* __restrict__ A,
                                                const unsigned short* __restrict__ W,
                                                const float* __restrict__ bias,
                                                unsigned short* __restrict__ C16,
                                                int ntiles, int N, int K) {
    __shared__ unsigned short Al[256 * 64];   // 32 KB
    __shared__ unsigned short Bl[128 * 64];   // 16 KB
    const int tid = threadIdx.x;
    const int lane = tid & 63, wave = tid >> 6;      // 0..7
    const int wm = wave >> 1, wn = wave & 1;         // 4M x 2N
    const int id = xcd_swz((int)blockIdx.x, (int)gridDim.x);
    const int n0 = (id % ntiles) * 128, m0 = (id / ntiles) * 256;
    const int c = lane >> 4, a15 = lane & 15;
    f32x4 acc[4][4] = {};

    const int srow = lane >> 3;
    const int sgran = (lane & 7) ^ srow;
    const int KT = K >> 6;

    for (int kt = 0; kt < KT; ++kt) {
        const int k0 = kt << 6;
        __syncthreads();
#pragma unroll
        for (int q = 0; q < 4; ++q) {
            const int rbase = wave * 32 + q * 8;
            gload_lds16(A + (size_t)(m0 + rbase + srow) * K + k0 + sgran * 8,
                        &Al[rbase * 64]);
        }
#pragma unroll
        for (int q = 0; q < 2; ++q) {
            const int rbase = wave * 16 + q * 8;
            gload_lds16(W + (size_t)(n0 + rbase + srow) * K + k0 + sgran * 8,
                        &Bl[rbase * 64]);
        }
        __syncthreads();
#pragma unroll
        for (int kc = 0; kc < 2; ++kc) {
            short8 af[4], bf[4];
#pragma unroll
            for (int fm = 0; fm < 4; ++fm) {
                const int row = wm * 64 + fm * 16 + a15;
                const int slot = (kc * 4 + c) ^ (row & 7);
                af[fm] = *(const short8*)&Al[row * 64 + slot * 8];
            }
#pragma unroll
            for (int fn = 0; fn < 4; ++fn) {
                const int row = wn * 64 + fn * 16 + a15;
                const int slot = (kc * 4 + c) ^ (row & 7);
                bf[fn] = *(const short8*)&Bl[row * 64 + slot * 8];
            }
#pragma unroll
            for (int fm = 0; fm < 4; ++fm)
#pragma unroll
                for (int fn = 0; fn < 4; ++fn)
                    acc[fm][fn] = __builtin_amdgcn_mfma_f32_16x16x32_bf16(
                        af[fm], bf[fn], acc[fm][fn], 0, 0, 0);
        }
    }
#pragma unroll
    for (int fn = 0; fn < 4; ++fn) {
        const int col = n0 + wn * 64 + fn * 16 + a15;
        const float bv = bias[col];
#pragma unroll
        for (int fm = 0; fm < 4; ++fm) {
            const int mrow = m0 + wm * 64 + fm * 16 + c * 4;
#pragma unroll
            for (int r = 0; r < 4; ++r) {
                float v = acc[fm][fn][r] + bv;
                if constexpr (RELU) v = fmaxf(v, 0.f);
                if constexpr (OUT16) C16[(size_t)(mrow + r) * N + col] = f2bf(v);
            }
        }
    }
}

// ------------- 8-wave fused GEMM + residual + LayerNorm (64x256) -------------
// Y = LN(A@W^T + bias + R); N fixed = 256. 64x256 tile, 8 waves (2M x 4N),
// dbuf + counted vmcnt(5) (5 gloads/thread/stage). Grid 256, slab-aligned.
// Halves W re-read traffic vs the 32-row version while keeping 8 waves/CU.
__global__ __launch_bounds__(512) void k_gemm_ln8(const unsigned short* __restrict__ A,
                                                  const unsigned short* __restrict__ W,
                                                  const float* __restrict__ bias,
                                                  const float* __restrict__ R,
                                                  const float* __restrict__ lns,
                                                  const float* __restrict__ lnb,
                                                  float* __restrict__ Y32,
                                                  unsigned short* __restrict__ Y16,
                                                  int K) {
    __shared__ unsigned short Al[64 * 64 * 2];    // 16 KB
    __shared__ unsigned short Bl[256 * 64 * 2];   // 64 KB
    __shared__ float redS[8][32];
    __shared__ float redQ[8][32];
    const int tid = threadIdx.x;
    const int lane = tid & 63, wave = tid >> 6;   // 0..7
    const int wm = wave >> 2, wn = wave & 3;      // 2M x 4N
    const int m0 = xcd_swz((int)blockIdx.x, (int)gridDim.x) * 64;
    const int c = lane >> 4, a15 = lane & 15;
    f32x4 acc[2][4] = {};

    const int srow = lane >> 3;
    const int sgran = (lane & 7) ^ srow;
    const int KT = K >> 6;

    auto stage = [&](int buf, int kt) {
        const int k0 = kt << 6;
        // A: 8 chunks of 8 rows; wave stages chunk `wave`
        gload_lds16(A + (size_t)(m0 + wave * 8 + srow) * K + k0 + sgran * 8,
                    &Al[buf * 4096 + (wave * 8) * 64]);
        // B: 32 chunks; wave stages rows wave*32 + q*8
#pragma unroll
        for (int q = 0; q < 4; ++q) {
            const int rbase = wave * 32 + q * 8;
            gload_lds16(W + (size_t)(rbase + srow) * K + k0 + sgran * 8,
                        &Bl[buf * 16384 + rbase * 64]);
        }
    };
    auto compute = [&](int buf) {
        const int ao = buf * 4096, bo = buf * 16384;
#pragma unroll
        for (int kc = 0; kc < 2; ++kc) {
            short8 af[2], bf[4];
#pragma unroll
            for (int fm = 0; fm < 2; ++fm) {
                const int row = wm * 32 + fm * 16 + a15;
                const int slot = (kc * 4 + c) ^ (row & 7);
                af[fm] = *(const short8*)&Al[ao + row * 64 + slot * 8];
            }
#pragma unroll
            for (int fn = 0; fn < 4; ++fn) {
                const int row = wn * 64 + fn * 16 + a15;
                const int slot = (kc * 4 + c) ^ (row & 7);
                bf[fn] = *(const short8*)&Bl[bo + row * 64 + slot * 8];
            }
#pragma unroll
            for (int fm = 0; fm < 2; ++fm)
#pragma unroll
                for (int fn = 0; fn < 4; ++fn)
                    acc[fm][fn] = __builtin_amdgcn_mfma_f32_16x16x32_bf16(
                        af[fm], bf[fn], acc[fm][fn], 0, 0, 0);
        }
    };

    stage(0, 0);
    for (int kt = 0; kt < KT; ++kt) {
        const int cur = kt & 1;
        if (kt + 1 < KT) {
            stage(cur ^ 1, kt + 1);
            asm volatile("s_waitcnt vmcnt(5)" ::: "memory");
        } else {
            asm volatile("s_waitcnt vmcnt(0)" ::: "memory");
        }
        __builtin_amdgcn_s_barrier();
        compute(cur);
        __builtin_amdgcn_s_barrier();
    }

    // ---- epilogue: v = acc + bias + R; LN over 256 cols per row ----
    float bv[4], sg[4], bg[4];
#pragma unroll
    for (int fn = 0; fn < 4; ++fn) {
        const int col = wn * 64 + fn * 16 + a15;
        bv[fn] = bias[col]; sg[fn] = lns[col]; bg[fn] = lnb[col];
    }
#pragma unroll
    for (int fm = 0; fm < 2; ++fm) {
        const int mrow = m0 + wm * 32 + fm * 16 + c * 4;
#pragma unroll
        for (int r = 0; r < 4; ++r) {
            float ps = 0.f, pq = 0.f;
#pragma unroll
            for (int fn = 0; fn < 4; ++fn) {
                const int col = wn * 64 + fn * 16 + a15;
                float v = acc[fm][fn][r] + bv[fn] + R[(size_t)(mrow + r) * Dm + col];
                acc[fm][fn][r] = v;
                ps += v; pq += v * v;
            }
#pragma unroll
            for (int off = 1; off < 16; off <<= 1) {
                ps += __shfl_xor(ps, off);
                pq += __shfl_xor(pq, off);
            }
            if (a15 == 0) {
                redS[wave][fm * 16 + c * 4 + r] = ps;
                redQ[wave][fm * 16 + c * 4 + r] = pq;
            }
        }
    }
    __syncthreads();
#pragma unroll
    for (int fm = 0; fm < 2; ++fm) {
        const int lrow = fm * 16 + c * 4;
        const int mrow = m0 + wm * 32 + lrow;
#pragma unroll
        for (int r = 0; r < 4; ++r) {
            const int g = wm * 4;
            const float totS = redS[g + 0][lrow + r] + redS[g + 1][lrow + r] +
                               redS[g + 2][lrow + r] + redS[g + 3][lrow + r];
            const float totQ = redQ[g + 0][lrow + r] + redQ[g + 1][lrow + r] +
                               redQ[g + 2][lrow + r] + redQ[g + 3][lrow + r];
            const float mean = totS * (1.f / 256.f);
            const float var = totQ * (1.f / 256.f) - mean * mean;
            const float inv = rsqrtf(var + 1e-5f);
#pragma unroll
            for (int fn = 0; fn < 4; ++fn) {
                const int col = wn * 64 + fn * 16 + a15;
                const float y = (acc[fm][fn][r] - mean) * inv * sg[fn] + bg[fn];
                Y32[(size_t)(mrow + r) * Dm + col] = y;
                Y16[(size_t)(mrow + r) * Dm + col] = f2bf(y);
            }
        }
    }
}

// ------------------------- MFMA flash attention -----------------------------
__global__ __launch_bounds__(512) void k_attn(const unsigned short* __restrict__ QKV,
                                              unsigned short* __restrict__ O) {
    __shared__ unsigned short Kl[512 * 32];   // [k][d], XOR-swizzled 16B granules
    __shared__ unsigned short Vt[32 * 512];   // [d][k], XOR-swizzled 8B granules
    const int bh = xcd_swz((int)blockIdx.x, (int)gridDim.x);
    const int b = bh >> 3, h = bh & 7;
    const int tid = threadIdx.x, lane = tid & 63, wave = tid >> 6;
    const int c = lane >> 4, a15 = lane & 15;
    const size_t qkvbase = (size_t)b * Lq * 768 + h * 32;

    {
        const int srow = lane >> 2;
        const int sg = (lane & 3) ^ ((srow >> 1) & 3);
#pragma unroll
        for (int q = 0; q < 4; ++q) {
            const int rbase = wave * 64 + q * 16;
            gload_lds16(QKV + qkvbase + (size_t)(rbase + srow) * 768 + 256 + sg * 8,
                        &Kl[rbase * 32]);
        }
    }
    {
        const int kg = tid & 127, dg = tid >> 7;
        u32x4 v[4];
#pragma unroll
        for (int kk = 0; kk < 4; ++kk)
            v[kk] = *(const u32x4*)&QKV[qkvbase + (size_t)(kg * 4 + kk) * 768 + 512 + dg * 8];
#pragma unroll
        for (int dd = 0; dd < 8; ++dd) {
            const int d = dg * 8 + dd;
            unsigned short e[4];
#pragma unroll
            for (int kk = 0; kk < 4; ++kk) {
                const unsigned int word = v[kk][dd >> 1];
                e[kk] = (dd & 1) ? (unsigned short)(word >> 16) : (unsigned short)(word & 0xffff);
            }
            unsigned int pk[2];
            pk[0] = (unsigned int)e[0] | ((unsigned int)e[1] << 16);
            pk[1] = (unsigned int)e[2] | ((unsigned int)e[3] << 16);
            *(uint2*)&Vt[d * 512 + ((kg ^ (d & 7)) << 2)] = *(uint2*)pk;
        }
    }
    const int q0w = wave * 64;
    short8 qf[4];
#pragma unroll
    for (int fn = 0; fn < 4; ++fn)
        qf[fn] = *(const short8*)&QKV[qkvbase + (size_t)(q0w + fn * 16 + a15) * 768 + c * 8];
    __syncthreads();

    const float scale = 0.17677669529663687f;   // 1/sqrt(32)
    f32x4 oacc[2][4] = {};
    float mstat[4], lstat[4];
#pragma unroll
    for (int fn = 0; fn < 4; ++fn) { mstat[fn] = -1e30f; lstat[fn] = 0.f; }
    const f32x4 zero4 = {0.f, 0.f, 0.f, 0.f};

    for (int t = 0; t < 16; ++t) {
        const int kv0 = t * 32;
        short8 kf[2];
#pragma unroll
        for (int fm = 0; fm < 2; ++fm) {
            const int row = kv0 + fm * 16 + a15;
            const int slot = c ^ ((row >> 1) & 3);
            kf[fm] = *(const short8*)&Kl[row * 32 + slot * 8];
        }
        short8 vf[2];
#pragma unroll
        for (int fmd = 0; fmd < 2; ++fmd) {
            const int d = fmd * 16 + a15;
            const int g0 = (t * 8 + c) ^ (d & 7);
            const int g1 = (t * 8 + 4 + c) ^ (d & 7);
            const u32x2 r0 = *(const u32x2*)&Vt[d * 512 + g0 * 4];
            const u32x2 r1 = *(const u32x2*)&Vt[d * 512 + g1 * 4];
            const u32x4 cmb = {r0[0], r0[1], r1[0], r1[1]};
            vf[fmd] = __builtin_bit_cast(short8, cmb);
        }
        f32x4 s[2][4];
#pragma unroll
        for (int fm = 0; fm < 2; ++fm)
#pragma unroll
            for (int fn = 0; fn < 4; ++fn)
                s[fm][fn] = __builtin_amdgcn_mfma_f32_16x16x32_bf16(kf[fm], qf[fn], zero4, 0, 0, 0);
#pragma unroll
        for (int fn = 0; fn < 4; ++fn) {
            float p[8];
            float tmax = -1e30f;
#pragma unroll
            for (int fm = 0; fm < 2; ++fm)
#pragma unroll
                for (int r = 0; r < 4; ++r) {
                    const float x = s[fm][fn][r] * scale;
                    p[fm * 4 + r] = x;
                    tmax = fmaxf(tmax, x);
                }
            tmax = fmaxf(tmax, __shfl_xor(tmax, 16));
            tmax = fmaxf(tmax, __shfl_xor(tmax, 32));
            const float mnew = fmaxf(mstat[fn], tmax);
            const float alpha = __expf(mstat[fn] - mnew);
            mstat[fn] = mnew;
            float tsum = 0.f;
            short8 pf;
#pragma unroll
            for (int j = 0; j < 8; ++j) {
                const float e = __expf(p[j] - mnew);
                tsum += e;
                pf[j] = (short)f2bf(e);
            }
            tsum += __shfl_xor(tsum, 16);
            tsum += __shfl_xor(tsum, 32);
            lstat[fn] = lstat[fn] * alpha + tsum;
#pragma unroll
            for (int fmd = 0; fmd < 2; ++fmd) {
                oacc[fmd][fn] *= alpha;
                oacc[fmd][fn] = __builtin_amdgcn_mfma_f32_16x16x32_bf16(
                    vf[fmd], pf, oacc[fmd][fn], 0, 0, 0);
            }
        }
    }
#pragma unroll
    for (int fn = 0; fn < 4; ++fn) {
        const float invl = 1.f / lstat[fn];
        const size_t qrow = (size_t)(b * Lq + q0w + fn * 16 + a15);
#pragma unroll
        for (int fmd = 0; fmd < 2; ++fmd)
#pragma unroll
            for (int r = 0; r < 4; ++r)
                O[qrow * Dm + h * 32 + fmd * 16 + c * 4 + r] = f2bf(oacc[fmd][fn][r] * invl);
    }
}

// ------------------------------- launcher ----------------------------------
extern "C" void kernel_launch(void* const* d_in, const int* in_sizes, int n_in,
                              void* d_out, int out_size, void* d_ws, size_t ws_size,
                              hipStream_t stream) {
    const float* image  = (const float*)d_in[0];
    const float* mask   = (const float*)d_in[1];
    const float* conv_w = (const float*)d_in[2];
    const float* conv_b = (const float*)d_in[3];
    const float* pos    = (const float*)d_in[4];
    const float* qkv_w  = (const float*)d_in[5];
    const float* qkv_b  = (const float*)d_in[6];
    const float* out_w  = (const float*)d_in[7];
    const float* out_b  = (const float*)d_in[8];
    const float* ln1_s  = (const float*)d_in[9];
    const float* ln1_b  = (const float*)d_in[10];
    const float* ff1_w  = (const float*)d_in[11];
    const float* ff1_b  = (const float*)d_in[12];
    const float* ff2_w  = (const float*)d_in[13];
    const float* ff2_b  = (const float*)d_in[14];
    const float* ln2_s  = (const float*)d_in[15];
    const float* ln2_b  = (const float*)d_in[16];
    float* out = (float*)d_out;

    char* w = (char*)d_ws;
    int* order            = (int*)w;            w += 64 * 1024;
    float* H32            = (float*)w;          w += (size_t)Mtok * Dm * 4;
    unsigned short* H16   = (unsigned short*)w; w += (size_t)Mtok * Dm * 2;
    unsigned short* QKV16 = (unsigned short*)w; w += (size_t)Mtok * 768 * 2;
    unsigned short* O16   = (unsigned short*)w; w += (size_t)Mtok * Dm * 2;
    unsigned short* F16   = (unsigned short*)w; w += (size_t)Mtok * FFq * 2;
    unsigned short* Wq    = (unsigned short*)w; w += (size_t)4 * 768 * 256 * 2;
    unsigned short* Wo    = (unsigned short*)w; w += (size_t)4 * 256 * 256 * 2;
    unsigned short* Wf1   = (unsigned short*)w; w += (size_t)4 * 2048 * 256 * 2;
    unsigned short* Wf2   = (unsigned short*)w; w += (size_t)4 * 256 * 2048 * 2;
    unsigned short* We    = (unsigned short*)w; w += (size_t)256 * 768 * 2;
    // embed-only buffers alias F16 (42 MB < 64 MB; dead before F16 written)
    unsigned short* patchA = F16;
    float* posG            = (float*)(F16 + (size_t)Mtok * 768);

    k_order<<<Bq, 1024, 0, stream>>>(mask, order);
    k_gather<<<Mtok / 16, 256, 0, stream>>>(image, order, pos, patchA, posG);
    k_wembed<<<96, 256, 0, stream>>>(conv_w, We);
    k_wprep_all<<<1280, 256, 0, stream>>>(qkv_w, out_w, ff1_w, ff2_w, Wq, Wo, Wf1, Wf2);

    // patch-embed GEMM: [16384,768] @ We^T + conv_b + posG -> H32, H16 (dbuf)
    k_mgemm<false, true, true, true, 2, true><<<256, 256, 0, stream>>>(
        patchA, We, conv_b, posG, H32, H16, 2, Mtok, 256, 768);

    for (int i = 0; i < 4; ++i) {
        // qkv projection -> QKV16; 256x128 tile, 384 blocks, slab-aligned
        k_mgemm8<false, true><<<384, 512, 0, stream>>>(
            H16, Wq + (size_t)i * 768 * 256, qkv_b + (size_t)i * 768,
            QKV16, 6, 768, 256);
        // attention -> O16 (bf16); slab-aligned swizzle
        k_attn<<<Bq * Hh, 512, 0, stream>>>(QKV16, O16);
        // out-proj + residual(H32) + LN1 -> H32, H16; 64-row tile, 8 waves
        k_gemm_ln8<<<Mtok / 64, 512, 0, stream>>>(
            O16, Wo + (size_t)i * 256 * 256, out_b + (size_t)i * 256, H32,
            ln1_s + i * Dm, ln1_b + i * Dm, H32, H16, 256);
        // ff1 + ReLU -> F16; 256x128 tile, 1024 blocks, slab-aligned
        k_mgemm8<true, true><<<1024, 512, 0, stream>>>(
            H16, Wf1 + (size_t)i * 2048 * 256, ff1_b + (size_t)i * FFq,
            F16, 16, 2048, 256);
        // ff2 + residual(H32) + LN2 -> (H32 or out), H16; 64-row tile, 8 waves
        float* dst32 = (i == 3) ? out : H32;
        k_gemm_ln8<<<Mtok / 64, 512, 0, stream>>>(
            F16, Wf2 + (size_t)i * 256 * 2048, ff2_b + (size_t)i * 256, H32,
            ln2_s + i * Dm, ln2_b + i * Dm, dst32, H16, 2048);
    }
    (void)in_sizes; (void)n_in; (void)out_size; (void)ws_size;
}

// Round 14
// 548.883 us; speedup vs baseline: 1.0273x; 1.0273x over previous
//
#include <hip/hip_runtime.h>
#include <cstdint>
#include <cstddef>

// ---------------------------------------------------------------------------
// MaskedContextEncoder: B=32 IMG=512 P=16 CIN=4 D=256 DEPTH=4 H=8 FF=2048
// Round 14: REVERT R13's 64x256 LN-GEMM (563.9us; 81KB LDS -> 1 block/CU ->
// single barrier domain, tails exposed -- R7's failure mode at scale). Back
// to R12's 32x256/4-wave k_gemm_ln (2 blocks/CU, 552.6us). Plus: fold
// k_wembed into k_wprep_all (one fewer dispatch).
// ---------------------------------------------------------------------------

#define Bq 32
#define Dm 256
#define Lq 512
#define Hh 8
#define FFq 2048
#define Mtok (Bq * Lq)   // 16384 rows

typedef __attribute__((ext_vector_type(8))) short  short8;
typedef __attribute__((ext_vector_type(4))) float  f32x4;
typedef __attribute__((ext_vector_type(4))) unsigned int u32x4;
typedef __attribute__((ext_vector_type(2))) unsigned int u32x2;

static __device__ __forceinline__ unsigned short f2bf(float f) {
    unsigned int u = __float_as_uint(f);
    unsigned int r = (u + 0x7FFFu + ((u >> 16) & 1u)) >> 16;
    return (unsigned short)r;
}
static __device__ __forceinline__ unsigned int pk2bf(float lo, float hi) {
    return (unsigned int)f2bf(lo) | ((unsigned int)f2bf(hi) << 16);
}

static __device__ __forceinline__ void gload_lds16(const void* g, void* l) {
    __builtin_amdgcn_global_load_lds(
        (const __attribute__((address_space(1))) unsigned int*)g,
        (__attribute__((address_space(3))) unsigned int*)l, 16, 0, 0);
}

// chunked bijective XCD swizzle: grid%8==0; XCD x gets logical ids
// [x*(grid/8), (x+1)*(grid/8)).
static __device__ __forceinline__ int xcd_swz(int id, int grid) {
    return (id & 7) * (grid >> 3) + (id >> 3);
}

// --------------------------- order (compaction) ----------------------------
__global__ __launch_bounds__(1024) void k_order(const float* __restrict__ mask,
                                                int* __restrict__ order) {
    const int b = blockIdx.x;
    const int n = threadIdx.x;
    const float v = mask[(size_t)b * 262144 + (size_t)(n >> 5) * 8192 + (n & 31) * 16];
    const bool sel = v < 0.5f;
    const unsigned long long ball = __ballot(sel);
    const int wave = n >> 6, lane = n & 63;
    __shared__ int wsum[16];
    __shared__ int wpre[16];
    if (lane == 0) wsum[wave] = __popcll(ball);
    __syncthreads();
    if (n == 0) {
        int s = 0;
        for (int i = 0; i < 16; ++i) { wpre[i] = s; s += wsum[i]; }
    }
    __syncthreads();
    const int rank = wpre[wave] + __popcll(ball & ((1ull << lane) - 1ull));
    if (sel) order[b * Lq + rank] = n;
}

// ----------------- gather: patches -> bf16 A, pos rows -> f32 ---------------
__global__ __launch_bounds__(256) void k_gather(const float* __restrict__ image,
                                                const int* __restrict__ order,
                                                const float* __restrict__ pos,
                                                unsigned short* __restrict__ patchA,
                                                float* __restrict__ posG) {
    __shared__ int pn[16];
    const int tid = threadIdx.x;
    const int tok0 = blockIdx.x * 16;
    if (tid < 16) pn[tid] = order[tok0 + tid];
    __syncthreads();
    const int lane = tid & 63, w4 = tid >> 6;
    const int rr = lane >> 2, col4 = (lane & 3) << 2;
#pragma unroll
    for (int it = 0; it < 12; ++it) {
        const int s = it * 4 + w4;          // 0..47 slabs (t,c)
        const int t = s / 3, cch = s % 3;
        const int n = pn[t];
        const int b = (tok0 + t) >> 9;
        const int pi = n >> 5, pj = n & 31;
        const float4 v = *(const float4*)&image[
            (((size_t)b * 3 + cch) * 512 + pi * 16 + rr) * 512 + pj * 16 + col4];
        unsigned int pk[2] = {pk2bf(v.x, v.y), pk2bf(v.z, v.w)};
        *(uint2*)&patchA[(size_t)(tok0 + t) * 768 + cch * 256 + rr * 16 + col4] =
            *(uint2*)pk;
    }
#pragma unroll
    for (int it = 0; it < 4; ++it) {
        const int t = it * 4 + w4;
        *(float4*)&posG[(size_t)(tok0 + t) * Dm + lane * 4] =
            *(const float4*)&pos[(size_t)pn[t] * Dm + lane * 4];
    }
}

// ---- merged weight prep: f32 [K][N] -> bf16 [N][K] + conv_w cast/truncate ---
// tiles: qkv 192 | out 64 | ff1 512 | ff2 512 | wembed 96 (blocks 1280..1375)
__global__ __launch_bounds__(256) void k_wprep_all(const float* __restrict__ qkv_w,
                                                   const float* __restrict__ out_w,
                                                   const float* __restrict__ ff1_w,
                                                   const float* __restrict__ ff2_w,
                                                   const float* __restrict__ conv_w,
                                                   unsigned short* __restrict__ Wq,
                                                   unsigned short* __restrict__ Wo,
                                                   unsigned short* __restrict__ Wf1,
                                                   unsigned short* __restrict__ Wf2,
                                                   unsigned short* __restrict__ We) {
    int idx = blockIdx.x;
    if (idx >= 1280) {
        // conv weight: f32 [256][1024] -> bf16 [256][768] (strip mask channel)
        const int i = (idx - 1280) * 256 + threadIdx.x;
        const int d = i / 96, k8 = (i % 96) * 8;
        const float4 a = *(const float4*)&conv_w[(size_t)d * 1024 + k8];
        const float4 b = *(const float4*)&conv_w[(size_t)d * 1024 + k8 + 4];
        unsigned int pk[4] = {pk2bf(a.x, a.y), pk2bf(a.z, a.w),
                              pk2bf(b.x, b.y), pk2bf(b.z, b.w)};
        *(uint4*)&We[(size_t)d * 768 + k8] = *(uint4*)pk;
        return;
    }
    __shared__ float tile[64][65];
    const float* W; unsigned short* WT; int K, N, l, r;
    if (idx < 192)      { l = idx / 48;          r = idx % 48;  K = 256;  N = 768;  W = qkv_w; WT = Wq; }
    else if (idx < 256) { l = (idx - 192) / 16;  r = idx & 15;  K = 256;  N = 256;  W = out_w; WT = Wo; }
    else if (idx < 768) { l = (idx - 256) / 128; r = (idx - 256) % 128; K = 256;  N = 2048; W = ff1_w; WT = Wf1; }
    else                { l = (idx - 768) / 128; r = (idx - 768) % 128; K = 2048; N = 256;  W = ff2_w; WT = Wf2; }
    const int nTiles = N >> 6;
    const int n0 = (r % nTiles) * 64, k0 = (r / nTiles) * 64;
    W  += (size_t)l * K * N;
    WT += (size_t)l * K * N;
    const int t = threadIdx.x;
#pragma unroll
    for (int it = 0; it < 4; ++it) {
        const int rr = (t >> 4) + it * 16, c4 = (t & 15) * 4;
        *(float4*)&tile[rr][c4] = *(const float4*)&W[(size_t)(k0 + rr) * N + n0 + c4];
    }
    __syncthreads();
    const int n = t & 63, kq = t >> 6;
    unsigned short pk[16];
#pragma unroll
    for (int j = 0; j < 16; ++j) pk[j] = f2bf(tile[kq * 16 + j][n]);
    unsigned short* dst = &WT[(size_t)(n0 + n) * K + k0 + kq * 16];
    *(uint4*)dst       = *(uint4*)&pk[0];
    *(uint4*)(dst + 8) = *(uint4*)&pk[8];
}

// ------------------------------ bf16 MFMA GEMM ------------------------------
// 128x128 tile, BK=64, 4 waves (2x2). Used for the embed GEMM.
template <bool RELU, bool RES, bool OUT32, bool OUT16, int NBUF, bool SWZ>
__global__ __launch_bounds__(256) void k_mgemm(const unsigned short* __restrict__ A,
                                               const unsigned short* __restrict__ W,
                                               const float* __restrict__ bias,
                                               const float* __restrict__ R,
                                               float* __restrict__ C32,
                                               unsigned short* __restrict__ C16,
                                               int ntiles, int M, int N, int K) {
    __shared__ unsigned short Al[128 * 64 * NBUF];
    __shared__ unsigned short Bl[128 * 64 * NBUF];
    const int tid = threadIdx.x;
    const int lane = tid & 63, wave = tid >> 6;
    const int wm = wave >> 1, wn = wave & 1;
    int id = blockIdx.x;
    if constexpr (SWZ) id = xcd_swz(id, (int)gridDim.x);
    const int n0 = (id % ntiles) * 128, m0 = (id / ntiles) * 128;
    const int c = lane >> 4, a15 = lane & 15;
    f32x4 acc[4][4] = {};

    const int srow = lane >> 3;
    const int sgran = (lane & 7) ^ srow;   // pre-swizzled source granule
    const int KT = K >> 6;

    auto stage = [&](int buf, int kt) {
        const int k0 = kt << 6;
#pragma unroll
        for (int q = 0; q < 4; ++q) {
            const int rbase = wave * 32 + q * 8;
            gload_lds16(A + (size_t)(m0 + rbase + srow) * K + k0 + sgran * 8,
                        &Al[buf * 8192 + rbase * 64]);
            gload_lds16(W + (size_t)(n0 + rbase + srow) * K + k0 + sgran * 8,
                        &Bl[buf * 8192 + rbase * 64]);
        }
    };
    auto compute = [&](int buf) {
        const int bo = buf * 8192;
#pragma unroll
        for (int kc = 0; kc < 2; ++kc) {
            short8 af[4], bf[4];
#pragma unroll
            for (int fm = 0; fm < 4; ++fm) {
                const int row = wm * 64 + fm * 16 + a15;
                const int slot = (kc * 4 + c) ^ (row & 7);
                af[fm] = *(const short8*)&Al[bo + row * 64 + slot * 8];
            }
#pragma unroll
            for (int fn = 0; fn < 4; ++fn) {
                const int row = wn * 64 + fn * 16 + a15;
                const int slot = (kc * 4 + c) ^ (row & 7);
                bf[fn] = *(const short8*)&Bl[bo + row * 64 + slot * 8];
            }
#pragma unroll
            for (int fm = 0; fm < 4; ++fm)
#pragma unroll
                for (int fn = 0; fn < 4; ++fn)
                    acc[fm][fn] = __builtin_amdgcn_mfma_f32_16x16x32_bf16(
                        af[fm], bf[fn], acc[fm][fn], 0, 0, 0);
        }
    };

    if constexpr (NBUF == 2) {
        stage(0, 0);
        for (int kt = 0; kt < KT; ++kt) {
            const int cur = kt & 1;
            if (kt + 1 < KT) {
                stage(cur ^ 1, kt + 1);
                asm volatile("s_waitcnt vmcnt(8)" ::: "memory");
            } else {
                asm volatile("s_waitcnt vmcnt(0)" ::: "memory");
            }
            __builtin_amdgcn_s_barrier();
            compute(cur);
            __builtin_amdgcn_s_barrier();
        }
    } else {
        for (int kt = 0; kt < KT; ++kt) {
            __syncthreads();
            stage(0, kt);
            __syncthreads();
            compute(0);
        }
    }
#pragma unroll
    for (int fn = 0; fn < 4; ++fn) {
        const int col = n0 + wn * 64 + fn * 16 + a15;
        const float bv = bias[col];
#pragma unroll
        for (int fm = 0; fm < 4; ++fm) {
            const int mrow = m0 + wm * 64 + fm * 16 + c * 4;
#pragma unroll
            for (int r = 0; r < 4; ++r) {
                float v = acc[fm][fn][r] + bv;
                if constexpr (RES) v += R[(size_t)(mrow + r) * N + col];
                if constexpr (RELU) v = fmaxf(v, 0.f);
                if constexpr (OUT32) C32[(size_t)(mrow + r) * N + col] = v;
                if constexpr (OUT16) C16[(size_t)(mrow + r) * N + col] = f2bf(v);
            }
        }
    }
}

// --------------------- 8-wave 256x128-tile bf16 MFMA GEMM -------------------
// 512 thr, 8 waves (4M x 2N), BK=64, single-buffer. Slab-aligned swizzle.
template <bool RELU, bool OUT16>
__global__ __launch_bounds__(512) void k_mgemm8(const unsigned short* __restrict__ A,
                                                const unsigned short* __restrict__ W,
                                                const float* __restrict__ bias,
                                                unsigned short* __restrict__ C16,
                                                int ntiles, int N, int K) {
    __shared__ unsigned short Al[256 * 64];   // 32 KB
    __shared__ unsigned short Bl[128 * 64];   // 16 KB
    const int tid = threadIdx.x;
    const int lane = tid & 63, wave = tid >> 6;      // 0..7
    const int wm = wave >> 1, wn = wave & 1;         // 4M x 2N
    const int id = xcd_swz((int)blockIdx.x, (int)gridDim.x);
    const int n0 = (id % ntiles) * 128, m0 = (id / ntiles) * 256;
    const int c = lane >> 4, a15 = lane & 15;
    f32x4 acc[4][4] = {};

    const int srow = lane >> 3;
    const int sgran = (lane & 7) ^ srow;
    const int KT = K >> 6;

    for (int kt = 0; kt < KT; ++kt) {
        const int k0 = kt << 6;
        __syncthreads();
#pragma unroll
        for (int q = 0; q < 4; ++q) {
            const int rbase = wave * 32 + q * 8;
            gload_lds16(A + (size_t)(m0 + rbase + srow) * K + k0 + sgran * 8,
                        &Al[rbase * 64]);
        }
#pragma unroll
        for (int q = 0; q < 2; ++q) {
            const int rbase = wave * 16 + q * 8;
            gload_lds16(W + (size_t)(n0 + rbase + srow) * K + k0 + sgran * 8,
                        &Bl[rbase * 64]);
        }
        __syncthreads();
#pragma unroll
        for (int kc = 0; kc < 2; ++kc) {
            short8 af[4], bf[4];
#pragma unroll
            for (int fm = 0; fm < 4; ++fm) {
                const int row = wm * 64 + fm * 16 + a15;
                const int slot = (kc * 4 + c) ^ (row & 7);
                af[fm] = *(const short8*)&Al[row * 64 + slot * 8];
            }
#pragma unroll
            for (int fn = 0; fn < 4; ++fn) {
                const int row = wn * 64 + fn * 16 + a15;
                const int slot = (kc * 4 + c) ^ (row & 7);
                bf[fn] = *(const short8*)&Bl[row * 64 + slot * 8];
            }
#pragma unroll
            for (int fm = 0; fm < 4; ++fm)
#pragma unroll
                for (int fn = 0; fn < 4; ++fn)
                    acc[fm][fn] = __builtin_amdgcn_mfma_f32_16x16x32_bf16(
                        af[fm], bf[fn], acc[fm][fn], 0, 0, 0);
        }
    }
#pragma unroll
    for (int fn = 0; fn < 4; ++fn) {
        const int col = n0 + wn * 64 + fn * 16 + a15;
        const float bv = bias[col];
#pragma unroll
        for (int fm = 0; fm < 4; ++fm) {
            const int mrow = m0 + wm * 64 + fm * 16 + c * 4;
#pragma unroll
            for (int r = 0; r < 4; ++r) {
                float v = acc[fm][fn][r] + bv;
                if constexpr (RELU) v = fmaxf(v, 0.f);
                if constexpr (OUT16) C16[(size_t)(mrow + r) * N + col] = f2bf(v);
            }
        }
    }
}

// -------------------- fused GEMM + residual + LayerNorm ----------------------
// Y = LN(A@W^T + bias + R) ; N fixed = 256. 32x256 tile, BK=64, 4 waves,
// dbuf + vmcnt(9). Grid 512 = 2 blocks/CU. XCD slab-aligned. (R12 version.)
__global__ __launch_bounds__(256) void k_gemm_ln(const unsigned short* __restrict__ A,
                                                 const unsigned short* __restrict__ W,
                                                 const float* __restrict__ bias,
                                                 const float* __restrict__ R,
                                                 const float* __restrict__ lns,
                                                 const float* __restrict__ lnb,
                                                 float* __restrict__ Y32,
                                                 unsigned short* __restrict__ Y16,
                                                 int K) {
    __shared__ unsigned short Al[32 * 64 * 2];    // 8 KB
    __shared__ unsigned short Bl[256 * 64 * 2];   // 64 KB
    __shared__ float redS[4][32];
    __shared__ float redQ[4][32];
    const int tid = threadIdx.x;
    const int lane = tid & 63, wave = tid >> 6;
    const int m0 = xcd_swz((int)blockIdx.x, (int)gridDim.x) * 32;
    const int c = lane >> 4, a15 = lane & 15;
    f32x4 acc[2][4] = {};

    const int srow = lane >> 3;
    const int sgran = (lane & 7) ^ srow;
    const int KT = K >> 6;

    auto stage = [&](int buf, int kt) {
        const int k0 = kt << 6;
        gload_lds16(A + (size_t)(m0 + wave * 8 + srow) * K + k0 + sgran * 8,
                    &Al[buf * 2048 + (wave * 8) * 64]);
#pragma unroll
        for (int q = 0; q < 8; ++q) {
            const int rbase = wave * 64 + q * 8;
            gload_lds16(W + (size_t)(rbase + srow) * K + k0 + sgran * 8,
                        &Bl[buf * 16384 + rbase * 64]);
        }
    };
    auto compute = [&](int buf) {
        const int ao = buf * 2048, bo = buf * 16384;
#pragma unroll
        for (int kc = 0; kc < 2; ++kc) {
            short8 af[2], bf[4];
#pragma unroll
            for (int fm = 0; fm < 2; ++fm) {
                const int row = fm * 16 + a15;
                const int slot = (kc * 4 + c) ^ (row & 7);
                af[fm] = *(const short8*)&Al[ao + row * 64 + slot * 8];
            }
#pragma unroll
            for (int fn = 0; fn < 4; ++fn) {
                const int row = wave * 64 + fn * 16 + a15;
                const int slot = (kc * 4 + c) ^ (row & 7);
                bf[fn] = *(const short8*)&Bl[bo + row * 64 + slot * 8];
            }
#pragma unroll
            for (int fm = 0; fm < 2; ++fm)
#pragma unroll
                for (int fn = 0; fn < 4; ++fn)
                    acc[fm][fn] = __builtin_amdgcn_mfma_f32_16x16x32_bf16(
                        af[fm], bf[fn], acc[fm][fn], 0, 0, 0);
        }
    };

    stage(0, 0);
    for (int kt = 0; kt < KT; ++kt) {
        const int cur = kt & 1;
        if (kt + 1 < KT) {
            stage(cur ^ 1, kt + 1);
            asm volatile("s_waitcnt vmcnt(9)" ::: "memory");
        } else {
            asm volatile("s_waitcnt vmcnt(0)" ::: "memory");
        }
        __builtin_amdgcn_s_barrier();
        compute(cur);
        __builtin_amdgcn_s_barrier();
    }

    float bv[4], sg[4], bg[4];
#pragma unroll
    for (int fn = 0; fn < 4; ++fn) {
        const int col = wave * 64 + fn * 16 + a15;
        bv[fn] = bias[col]; sg[fn] = lns[col]; bg[fn] = lnb[col];
    }
#pragma unroll
    for (int fm = 0; fm < 2; ++fm) {
        const int mrow = m0 + fm * 16 + c * 4;
#pragma unroll
        for (int r = 0; r < 4; ++r) {
            float ps = 0.f, pq = 0.f;
#pragma unroll
            for (int fn = 0; fn < 4; ++fn) {
                const int col = wave * 64 + fn * 16 + a15;
                float v = acc[fm][fn][r] + bv[fn] + R[(size_t)(mrow + r) * Dm + col];
                acc[fm][fn][r] = v;
                ps += v; pq += v * v;
            }
#pragma unroll
            for (int off = 1; off < 16; off <<= 1) {
                ps += __shfl_xor(ps, off);
                pq += __shfl_xor(pq, off);
            }
            if (a15 == 0) {
                redS[wave][fm * 16 + c * 4 + r] = ps;
                redQ[wave][fm * 16 + c * 4 + r] = pq;
            }
        }
    }
    __syncthreads();
#pragma unroll
    for (int fm = 0; fm < 2; ++fm) {
        const int lrow = fm * 16 + c * 4;
        const int mrow = m0 + lrow;
#pragma unroll
        for (int r = 0; r < 4; ++r) {
            const float totS = redS[0][lrow + r] + redS[1][lrow + r] +
                               redS[2][lrow + r] + redS[3][lrow + r];
            const float totQ = redQ[0][lrow + r] + redQ[1][lrow + r] +
                               redQ[2][lrow + r] + redQ[3][lrow + r];
            const float mean = totS * (1.f / 256.f);
            const float var = totQ * (1.f / 256.f) - mean * mean;
            const float inv = rsqrtf(var + 1e-5f);
#pragma unroll
            for (int fn = 0; fn < 4; ++fn) {
                const int col = wave * 64 + fn * 16 + a15;
                const float y = (acc[fm][fn][r] - mean) * inv * sg[fn] + bg[fn];
                Y32[(size_t)(mrow + r) * Dm + col] = y;
                Y16[(size_t)(mrow + r) * Dm + col] = f2bf(y);
            }
        }
    }
}

// ------------------------- MFMA flash attention -----------------------------
__global__ __launch_bounds__(512) void k_attn(const unsigned short* __restrict__ QKV,
                                              unsigned short* __restrict__ O) {
    __shared__ unsigned short Kl[512 * 32];   // [k][d], XOR-swizzled 16B granules
    __shared__ unsigned short Vt[32 * 512];   // [d][k], XOR-swizzled 8B granules
    const int bh = xcd_swz((int)blockIdx.x, (int)gridDim.x);
    const int b = bh >> 3, h = bh & 7;
    const int tid = threadIdx.x, lane = tid & 63, wave = tid >> 6;
    const int c = lane >> 4, a15 = lane & 15;
    const size_t qkvbase = (size_t)b * Lq * 768 + h * 32;

    {
        const int srow = lane >> 2;
        const int sg = (lane & 3) ^ ((srow >> 1) & 3);
#pragma unroll
        for (int q = 0; q < 4; ++q) {
            const int rbase = wave * 64 + q * 16;
            gload_lds16(QKV + qkvbase + (size_t)(rbase + srow) * 768 + 256 + sg * 8,
                        &Kl[rbase * 32]);
        }
    }
    {
        const int kg = tid & 127, dg = tid >> 7;
        u32x4 v[4];
#pragma unroll
        for (int kk = 0; kk < 4; ++kk)
            v[kk] = *(const u32x4*)&QKV[qkvbase + (size_t)(kg * 4 + kk) * 768 + 512 + dg * 8];
#pragma unroll
        for (int dd = 0; dd < 8; ++dd) {
            const int d = dg * 8 + dd;
            unsigned short e[4];
#pragma unroll
            for (int kk = 0; kk < 4; ++kk) {
                const unsigned int word = v[kk][dd >> 1];
                e[kk] = (dd & 1) ? (unsigned short)(word >> 16) : (unsigned short)(word & 0xffff);
            }
            unsigned int pk[2];
            pk[0] = (unsigned int)e[0] | ((unsigned int)e[1] << 16);
            pk[1] = (unsigned int)e[2] | ((unsigned int)e[3] << 16);
            *(uint2*)&Vt[d * 512 + ((kg ^ (d & 7)) << 2)] = *(uint2*)pk;
        }
    }
    const int q0w = wave * 64;
    short8 qf[4];
#pragma unroll
    for (int fn = 0; fn < 4; ++fn)
        qf[fn] = *(const short8*)&QKV[qkvbase + (size_t)(q0w + fn * 16 + a15) * 768 + c * 8];
    __syncthreads();

    const float scale = 0.17677669529663687f;   // 1/sqrt(32)
    f32x4 oacc[2][4] = {};
    float mstat[4], lstat[4];
#pragma unroll
    for (int fn = 0; fn < 4; ++fn) { mstat[fn] = -1e30f; lstat[fn] = 0.f; }
    const f32x4 zero4 = {0.f, 0.f, 0.f, 0.f};

    for (int t = 0; t < 16; ++t) {
        const int kv0 = t * 32;
        short8 kf[2];
#pragma unroll
        for (int fm = 0; fm < 2; ++fm) {
            const int row = kv0 + fm * 16 + a15;
            const int slot = c ^ ((row >> 1) & 3);
            kf[fm] = *(const short8*)&Kl[row * 32 + slot * 8];
        }
        short8 vf[2];
#pragma unroll
        for (int fmd = 0; fmd < 2; ++fmd) {
            const int d = fmd * 16 + a15;
            const int g0 = (t * 8 + c) ^ (d & 7);
            const int g1 = (t * 8 + 4 + c) ^ (d & 7);
            const u32x2 r0 = *(const u32x2*)&Vt[d * 512 + g0 * 4];
            const u32x2 r1 = *(const u32x2*)&Vt[d * 512 + g1 * 4];
            const u32x4 cmb = {r0[0], r0[1], r1[0], r1[1]};
            vf[fmd] = __builtin_bit_cast(short8, cmb);
        }
        f32x4 s[2][4];
#pragma unroll
        for (int fm = 0; fm < 2; ++fm)
#pragma unroll
            for (int fn = 0; fn < 4; ++fn)
                s[fm][fn] = __builtin_amdgcn_mfma_f32_16x16x32_bf16(kf[fm], qf[fn], zero4, 0, 0, 0);
#pragma unroll
        for (int fn = 0; fn < 4; ++fn) {
            float p[8];
            float tmax = -1e30f;
#pragma unroll
            for (int fm = 0; fm < 2; ++fm)
#pragma unroll
                for (int r = 0; r < 4; ++r) {
                    const float x = s[fm][fn][r] * scale;
                    p[fm * 4 + r] = x;
                    tmax = fmaxf(tmax, x);
                }
            tmax = fmaxf(tmax, __shfl_xor(tmax, 16));
            tmax = fmaxf(tmax, __shfl_xor(tmax, 32));
            const float mnew = fmaxf(mstat[fn], tmax);
            const float alpha = __expf(mstat[fn] - mnew);
            mstat[fn] = mnew;
            float tsum = 0.f;
            short8 pf;
#pragma unroll
            for (int j = 0; j < 8; ++j) {
                const float e = __expf(p[j] - mnew);
                tsum += e;
                pf[j] = (short)f2bf(e);
            }
            tsum += __shfl_xor(tsum, 16);
            tsum += __shfl_xor(tsum, 32);
            lstat[fn] = lstat[fn] * alpha + tsum;
#pragma unroll
            for (int fmd = 0; fmd < 2; ++fmd) {
                oacc[fmd][fn] *= alpha;
                oacc[fmd][fn] = __builtin_amdgcn_mfma_f32_16x16x32_bf16(
                    vf[fmd], pf, oacc[fmd][fn], 0, 0, 0);
            }
        }
    }
#pragma unroll
    for (int fn = 0; fn < 4; ++fn) {
        const float invl = 1.f / lstat[fn];
        const size_t qrow = (size_t)(b * Lq + q0w + fn * 16 + a15);
#pragma unroll
        for (int fmd = 0; fmd < 2; ++fmd)
#pragma unroll
            for (int r = 0; r < 4; ++r)
                O[qrow * Dm + h * 32 + fmd * 16 + c * 4 + r] = f2bf(oacc[fmd][fn][r] * invl);
    }
}

// ------------------------------- launcher ----------------------------------
extern "C" void kernel_launch(void* const* d_in, const int* in_sizes, int n_in,
                              void* d_out, int out_size, void* d_ws, size_t ws_size,
                              hipStream_t stream) {
    const float* image  = (const float*)d_in[0];
    const float* mask   = (const float*)d_in[1];
    const float* conv_w = (const float*)d_in[2];
    const float* conv_b = (const float*)d_in[3];
    const float* pos    = (const float*)d_in[4];
    const float* qkv_w  = (const float*)d_in[5];
    const float* qkv_b  = (const float*)d_in[6];
    const float* out_w  = (const float*)d_in[7];
    const float* out_b  = (const float*)d_in[8];
    const float* ln1_s  = (const float*)d_in[9];
    const float* ln1_b  = (const float*)d_in[10];
    const float* ff1_w  = (const float*)d_in[11];
    const float* ff1_b  = (const float*)d_in[12];
    const float* ff2_w  = (const float*)d_in[13];
    const float* ff2_b  = (const float*)d_in[14];
    const float* ln2_s  = (const float*)d_in[15];
    const float* ln2_b  = (const float*)d_in[16];
    float* out = (float*)d_out;

    char* w = (char*)d_ws;
    int* order            = (int*)w;            w += 64 * 1024;
    float* H32            = (float*)w;          w += (size_t)Mtok * Dm * 4;
    unsigned short* H16   = (unsigned short*)w; w += (size_t)Mtok * Dm * 2;
    unsigned short* QKV16 = (unsigned short*)w; w += (size_t)Mtok * 768 * 2;
    unsigned short* O16   = (unsigned short*)w; w += (size_t)Mtok * Dm * 2;
    unsigned short* F16   = (unsigned short*)w; w += (size_t)Mtok * FFq * 2;
    unsigned short* Wq    = (unsigned short*)w; w += (size_t)4 * 768 * 256 * 2;
    unsigned short* Wo    = (unsigned short*)w; w += (size_t)4 * 256 * 256 * 2;
    unsigned short* Wf1   = (unsigned short*)w; w += (size_t)4 * 2048 * 256 * 2;
    unsigned short* Wf2   = (unsigned short*)w; w += (size_t)4 * 256 * 2048 * 2;
    unsigned short* We    = (unsigned short*)w; w += (size_t)256 * 768 * 2;
    // embed-only buffers alias F16 (42 MB < 64 MB; dead before F16 written)
    unsigned short* patchA = F16;
    float* posG            = (float*)(F16 + (size_t)Mtok * 768);

    k_order<<<Bq, 1024, 0, stream>>>(mask, order);
    k_gather<<<Mtok / 16, 256, 0, stream>>>(image, order, pos, patchA, posG);
    k_wprep_all<<<1376, 256, 0, stream>>>(qkv_w, out_w, ff1_w, ff2_w, conv_w,
                                          Wq, Wo, Wf1, Wf2, We);

    // patch-embed GEMM: [16384,768] @ We^T + conv_b + posG -> H32, H16 (dbuf)
    k_mgemm<false, true, true, true, 2, true><<<256, 256, 0, stream>>>(
        patchA, We, conv_b, posG, H32, H16, 2, Mtok, 256, 768);

    for (int i = 0; i < 4; ++i) {
        // qkv projection -> QKV16; 256x128 tile, 384 blocks, slab-aligned
        k_mgemm8<false, true><<<384, 512, 0, stream>>>(
            H16, Wq + (size_t)i * 768 * 256, qkv_b + (size_t)i * 768,
            QKV16, 6, 768, 256);
        // attention -> O16 (bf16); slab-aligned swizzle
        k_attn<<<Bq * Hh, 512, 0, stream>>>(QKV16, O16);
        // out-proj + residual(H32) + LN1 -> H32, H16; 32-row tile (R12)
        k_gemm_ln<<<Mtok / 32, 256, 0, stream>>>(
            O16, Wo + (size_t)i * 256 * 256, out_b + (size_t)i * 256, H32,
            ln1_s + i * Dm, ln1_b + i * Dm, H32, H16, 256);
        // ff1 + ReLU -> F16; 256x128 tile, 1024 blocks, slab-aligned
        k_mgemm8<true, true><<<1024, 512, 0, stream>>>(
            H16, Wf1 + (size_t)i * 2048 * 256, ff1_b + (size_t)i * FFq,
            F16, 16, 2048, 256);
        // ff2 + residual(H32) + LN2 -> (H32 or out), H16; 32-row tile (R12)
        float* dst32 = (i == 3) ? out : H32;
        k_gemm_ln<<<Mtok / 32, 256, 0, stream>>>(
            F16, Wf2 + (size_t)i * 256 * 2048, ff2_b + (size_t)i * 256, H32,
            ln2_s + i * Dm, ln2_b + i * Dm, dst32, H16, 2048);
    }
    (void)in_sizes; (void)n_in; (void)out_size; (void)ws_size;
}